// Round 2
// baseline (254.667 us; speedup 1.0000x reference)
//
#include <hip/hip_runtime.h>

// Problem constants (match reference):
//   x:       [256, 3, 224, 224] fp32
//   patch:   [1, 3, 30, 30]     fp32
//   offsets: [256, 2]           int32, each in [0, 194)
//   out = x with patch added at per-sample (r, c).
#define ISIZE 224
#define PSIZE 30
#define BATCH 256
#define NCH   3

// Exact decomposition (no remainders):
//   floats/channel = 224*224 = 50176 -> 12544 float4 -> 49 blocks of 256 thr
//   blocks/image   = 3*49    = 147
//   grid           = (147, 256)
//
// Uniformity: b = blockIdx.y, ch = blockIdx.x/49 are wave-uniform, so the
// offsets loads become s_load and the patch-intersection test is one scalar
// branch. ~85% of blocks (patch rows cover 30/224 of each channel) take the
// pure copy path: global_load_dwordx4 -> global_store_dwordx4, nothing else.

__global__ __launch_bounds__(256)
void RandomPrompter_64982855189232_kernel(const float* __restrict__ x,
                                          const float* __restrict__ patch,
                                          const int* __restrict__ offsets,
                                          float* __restrict__ out) {
    constexpr int PER_ROW4   = ISIZE / 4;                 // 56
    constexpr int BLK_PER_CH = ISIZE * ISIZE / 4 / 256;   // 49
    constexpr int BLK_PER_IMG = NCH * BLK_PER_CH;         // 147

    const int bx  = blockIdx.x;   // [0,147) — position within image
    const int b   = blockIdx.y;   // [0,256) — batch index (uniform)
    const int tid = threadIdx.x;

    const int i4 = (b * BLK_PER_IMG + bx) * 256 + tid;

    const float4* __restrict__ x4 = (const float4*)x;
    float4* __restrict__ o4 = (float4*)out;

    // Kick the streaming load first.
    float4 v = x4[i4];

    const int ch   = bx / BLK_PER_CH;                     // uniform (scalar div)
    const int blk_base = (bx - ch * BLK_PER_CH) * 256;    // uniform
    const int rem2 = blk_base + tid;                      // [0,12544) within channel

    // Uniform scalar loads (address depends only on blockIdx.y).
    const int r = offsets[2 * b];
    const int c = offsets[2 * b + 1];

    // Block-level uniform intersection test: rows this block touches.
    const int row_lo = blk_base / PER_ROW4;
    const int row_hi = (blk_base + 255) / PER_ROW4;

    if (row_hi >= r && row_lo < r + PSIZE) {
        const int row = rem2 / PER_ROW4;
        const int col = (rem2 - row * PER_ROW4) * 4;
        const int pr  = row - r;
        if (pr >= 0 && pr < PSIZE) {
            const float* __restrict__ prow = patch + (ch * PSIZE + pr) * PSIZE;
            float* vf = (float*)&v;
#pragma unroll
            for (int j = 0; j < 4; ++j) {
                const int pc = col + j - c;
                if (pc >= 0 && pc < PSIZE) vf[j] += prow[pc];
            }
        }
    }
    o4[i4] = v;
}

extern "C" void kernel_launch(void* const* d_in, const int* in_sizes, int n_in,
                              void* d_out, int out_size, void* d_ws, size_t ws_size,
                              hipStream_t stream) {
    const float* x       = (const float*)d_in[0];
    const float* patch   = (const float*)d_in[1];
    const int*   offsets = (const int*)d_in[2];
    float*       out     = (float*)d_out;

    dim3 grid(NCH * (ISIZE * ISIZE / 4 / 256), BATCH);  // (147, 256)
    dim3 block(256);

    RandomPrompter_64982855189232_kernel<<<grid, block, 0, stream>>>(x, patch, offsets, out);
}

// Round 3
// 249.464 us; speedup vs baseline: 1.0209x; 1.0209x over previous
//
#include <hip/hip_runtime.h>

// Problem constants (match reference):
//   x:       [256, 3, 224, 224] fp32
//   patch:   [1, 3, 30, 30]     fp32
//   offsets: [256, 2]           int32, each in [0, 194)
//   out = x with patch added at per-sample (r, c).
#define ISIZE 224
#define PSIZE 30
#define BATCH 256
#define NCH   3

// True clang vector type so __builtin_nontemporal_load/store accepts it and
// still emits global_load_dwordx4 / global_store_dwordx4 (with nt cache bits).
typedef float f32x4 __attribute__((ext_vector_type(4)));

// Exact decomposition (no remainders):
//   floats/channel = 224*224 = 50176 -> 12544 float4 -> 49 blocks of 256 thr
//   blocks/image   = 3*49    = 147;  grid = (147, 256)
// b = blockIdx.y and ch = blockIdx.x/49 are uniform -> offsets are s_loads,
// patch-intersection test is one scalar branch; ~85% of blocks are a pure
// nt-load -> nt-store stream.

__global__ __launch_bounds__(256)
void RandomPrompter_64982855189232_kernel(const float* __restrict__ x,
                                          const float* __restrict__ patch,
                                          const int* __restrict__ offsets,
                                          float* __restrict__ out) {
    constexpr int PER_ROW4    = ISIZE / 4;                // 56
    constexpr int BLK_PER_CH  = ISIZE * ISIZE / 4 / 256;  // 49
    constexpr int BLK_PER_IMG = NCH * BLK_PER_CH;         // 147

    const int bx  = blockIdx.x;   // [0,147) — position within image
    const int b   = blockIdx.y;   // [0,256) — batch index (uniform)
    const int tid = threadIdx.x;

    const int i4 = (b * BLK_PER_IMG + bx) * 256 + tid;

    const f32x4* __restrict__ x4 = (const f32x4*)x;
    f32x4* __restrict__ o4 = (f32x4*)out;

    // Streaming (non-temporal) load: x is read exactly once — don't cache it.
    f32x4 v = __builtin_nontemporal_load(&x4[i4]);

    const int ch       = bx / BLK_PER_CH;                 // uniform
    const int blk_base = (bx - ch * BLK_PER_CH) * 256;    // uniform
    const int rem2     = blk_base + tid;                  // [0,12544) in channel

    // Uniform scalar loads (address depends only on blockIdx.y).
    const int r = offsets[2 * b];
    const int c = offsets[2 * b + 1];

    // Block-uniform intersection test on the rows this block covers.
    const int row_lo = blk_base / PER_ROW4;
    const int row_hi = (blk_base + 255) / PER_ROW4;

    if (row_hi >= r && row_lo < r + PSIZE) {
        const int row = rem2 / PER_ROW4;
        const int col = (rem2 - row * PER_ROW4) * 4;
        const int pr  = row - r;
        if (pr >= 0 && pr < PSIZE) {
            // Patch is tiny (10.8 KB) and reused by many blocks: cached loads.
            const float* __restrict__ prow = patch + (ch * PSIZE + pr) * PSIZE;
#pragma unroll
            for (int j = 0; j < 4; ++j) {
                const int pc = col + j - c;
                if (pc >= 0 && pc < PSIZE) v[j] += prow[pc];
            }
        }
    }
    // Streaming (non-temporal) store: out is written exactly once.
    __builtin_nontemporal_store(v, &o4[i4]);
}

extern "C" void kernel_launch(void* const* d_in, const int* in_sizes, int n_in,
                              void* d_out, int out_size, void* d_ws, size_t ws_size,
                              hipStream_t stream) {
    const float* x       = (const float*)d_in[0];
    const float* patch   = (const float*)d_in[1];
    const int*   offsets = (const int*)d_in[2];
    float*       out     = (float*)d_out;

    dim3 grid(NCH * (ISIZE * ISIZE / 4 / 256), BATCH);  // (147, 256)
    dim3 block(256);

    RandomPrompter_64982855189232_kernel<<<grid, block, 0, stream>>>(x, patch, offsets, out);
}